// Round 1
// baseline (191.644 us; speedup 1.0000x reference)
//
#include <hip/hip_runtime.h>
#include <math.h>

// Problem constants (shapes derived at runtime from in_sizes):
// N=500k points, C=1000 cells, L=16 clusters, G=500 genes, NT=10000 total genes,
// K=224 heights, W=221 widths, spline levels (128,64,32).
//
// Strategy: clustering is one-hot => spline params depend only on (gene,cluster)
// pair: G*L = 8000 pairs. Precompute per-pair per-level tables
// [locations(nb+1) | left_cdf(nb+1) | heights(nb+1) | widths(nb)] into d_ws,
// then each point does binary-search + O(1) eval per level.

#define TSTRIDE 896  // 511 + 255 + 127 = 893 floats per pair, padded
static constexpr float  F_MBW = 1e-3f;   // MIN_BIN_WIDTH
static constexpr float  F_MBH = 1e-3f;   // MIN_BIN_HEIGHT
static constexpr double D_HL2PI = 0.918938533204672741780329736406; // 0.5*log(2pi)

// ---------------- init: zero the f64 accumulators ----------------
__global__ void k_init(double* acc) {
  if (threadIdx.x < 4) acc[threadIdx.x] = 0.0;
}

// ---------------- per-cell cluster id (one-hot argmax) ----------------
__global__ void k_cluster(const float* __restrict__ clustering, int* __restrict__ cid,
                          int C, int L) {
  int c = blockIdx.x * blockDim.x + threadIdx.x;
  if (c >= C) return;
  const float* row = clustering + (size_t)c * L;
  int best = 0; float bv = row[0];
  for (int l = 1; l < L; ++l) { float v = row[l]; if (v > bv) { bv = v; best = l; } }
  cid[c] = best;
}

// ---------------- per-cluster logsumexp over NT genes ----------------
__global__ void __launch_bounds__(256)
k_lse(const float* __restrict__ bb, const float* __restrict__ dbw,
      float* __restrict__ lse, int NT, int L) {
  int l = blockIdx.x;
  int tid = threadIdx.x;
  __shared__ float red[256];
  float m = -INFINITY;
  for (int t = tid; t < NT; t += blockDim.x)
    m = fmaxf(m, logf(bb[t]) + dbw[(size_t)t * L + l]);
  red[tid] = m; __syncthreads();
  for (int off = 128; off > 0; off >>= 1) {
    if (tid < off) red[tid] = fmaxf(red[tid], red[tid + off]);
    __syncthreads();
  }
  m = red[0]; __syncthreads();
  float s = 0.f;
  for (int t = tid; t < NT; t += blockDim.x)
    s += expf(logf(bb[t]) + dbw[(size_t)t * L + l] - m);
  red[tid] = s; __syncthreads();
  for (int off = 128; off > 0; off >>= 1) {
    if (tid < off) red[tid] += red[tid + off];
    __syncthreads();
  }
  if (tid == 0) lse[l] = m + logf(red[0]);
}

// ---------------- inclusive Hillis-Steele scan in LDS ----------------
static __device__ __forceinline__ void scan_inc(float* buf, int n, int tid) {
  for (int off = 1; off < n; off <<= 1) {
    float v = 0.f;
    if (tid < n) { v = buf[tid]; if (tid >= off) v += buf[tid - off]; }
    __syncthreads();
    if (tid < n) buf[tid] = v;
    __syncthreads();
  }
}

// ---------------- build per-(gene,cluster) spline tables ----------------
__global__ void __launch_bounds__(128)
k_build(const float* __restrict__ uh, const float* __restrict__ uw,
        const float* __restrict__ dhw, const int* __restrict__ genes_oi,
        float* __restrict__ tables, int L, int K, int W) {
  int pair = blockIdx.x;          // g*L + l
  int g = pair / L;
  int l = pair - g * L;
  int gg = genes_oi[g];
  const float* uhg  = uh + (size_t)gg * K;
  const float* uwg  = uw + (size_t)gg * W;
  const float* drow = dhw + ((size_t)gg * L + l) * K;
  float* tb = tables + (size_t)pair * TSTRIDE;
  int tid = threadIdx.x;

  __shared__ float s_w[128];
  __shared__ float s_h[128];
  __shared__ float s_t[128];
  __shared__ float s_r[128];

  int ho = 0, wo = 0, toff = 0;
  for (int lev = 0; lev < 3; ++lev) {
    int nbp1 = (lev == 0) ? 128 : (lev == 1) ? 64 : 32;  // #heights = #locations
    int nb = nbp1 - 1;                                    // #width bins
    // ---- widths = affine(softmax(uw)) ----
    float wraw = (tid < nb) ? uwg[wo + tid] : -INFINITY;
    s_r[tid] = wraw; __syncthreads();
    for (int off = 64; off > 0; off >>= 1) {
      if (tid < off) s_r[tid] = fmaxf(s_r[tid], s_r[tid + off]);
      __syncthreads();
    }
    float wmax = s_r[0]; __syncthreads();
    float ew = (tid < nb) ? expf(wraw - wmax) : 0.f;
    s_r[tid] = ew; __syncthreads();
    for (int off = 64; off > 0; off >>= 1) {
      if (tid < off) s_r[tid] += s_r[tid + off];
      __syncthreads();
    }
    float wsum = s_r[0]; __syncthreads();
    float width = F_MBW + (1.0f - F_MBW * (float)nb) * (ew / wsum);
    if (tid < nb) s_w[tid] = width;
    // ---- heights: normalize piecewise-linear pdf ----
    float hexp = (tid < nbp1) ? expf(uhg[ho + tid] + drow[ho + tid]) : 0.f;
    s_h[tid] = hexp;
    __syncthreads();
    float aterm = (tid < nb) ? 0.5f * (s_h[tid] + s_h[tid + 1]) * width : 0.f;
    s_r[tid] = aterm; __syncthreads();
    for (int off = 64; off > 0; off >>= 1) {
      if (tid < off) s_r[tid] += s_r[tid + off];
      __syncthreads();
    }
    float area = s_r[0]; __syncthreads();
    float height = F_MBH + (1.0f - F_MBH) * (hexp / area);
    s_h[tid] = (tid < nbp1) ? height : 0.f;
    __syncthreads();
    float cterm = (tid < nb) ? 0.5f * (s_h[tid] + s_h[tid + 1]) * s_w[tid] : 0.f;
    s_t[tid] = cterm;
    __syncthreads();
    // ---- write heights & widths ----
    if (tid < nbp1) tb[toff + 2 * nbp1 + tid] = height;
    if (tid < nb)   tb[toff + 3 * nbp1 + tid] = width;
    // ---- locations = pad(cumsum(widths) with last:=1) ----
    scan_inc(s_w, nb, tid);
    if (tid == 0)              tb[toff] = 0.f;
    if (tid >= 1 && tid <= nb) tb[toff + tid] = (tid == nb) ? 1.0f : s_w[tid - 1];
    // ---- left_cdf = pad(cumsum(cdf_terms) with last:=1) ----
    scan_inc(s_t, nb, tid);
    if (tid == 0)              tb[toff + nbp1] = 0.f;
    if (tid >= 1 && tid <= nb) tb[toff + nbp1 + tid] = (tid == nb) ? 1.0f : s_t[tid - 1];
    __syncthreads();
    ho += nbp1; wo += nb; toff += 4 * nb + 3;
  }
}

// ---------------- main per-point evaluation ----------------
__global__ void __launch_bounds__(256)
k_main(const float* __restrict__ coords, const int* __restrict__ lgi,
       const int* __restrict__ lcg, const int* __restrict__ genes_oi,
       const int* __restrict__ cid, const float* __restrict__ lse,
       const float* __restrict__ bb, const float* __restrict__ dbw,
       const float* __restrict__ tables, double* __restrict__ acc,
       int N, int G, int L, int NT) {
  int n = blockIdx.x * blockDim.x + threadIdx.x;
  float contrib = 0.f;
  if (n < N) {
    float x = coords[n];
    int g = lgi[n];
    int c = lcg[n] / G;          // local_cellxgene_ix = cell*G + gene
    int cl = cid[c];
    const float* tb = tables + (size_t)(g * L + cl) * TSTRIDE;
    float lad = 0.f;
    int toff = 0;
    #pragma unroll
    for (int lev = 0; lev < 3; ++lev) {
      int nbp1 = (lev == 0) ? 128 : (lev == 1) ? 64 : 32;
      int nb = nbp1 - 1;
      const float* loc = tb + toff;
      const float* cdf = loc + nbp1;
      const float* hh  = cdf + nbp1;
      const float* ww  = hh + nbp1;
      // idx = clip((#locations <= x) - 1, 0, nb-1); loc[0]=0 <= x always
      int lo = 0, hi = nbp1;
      while (hi - lo > 1) {
        int mid = (lo + hi) >> 1;
        bool le = loc[mid] <= x;
        lo = le ? mid : lo;
        hi = le ? hi : mid;
      }
      int idx = (lo > nb - 1) ? (nb - 1) : lo;
      float w  = ww[idx];
      float lc = loc[idx];
      float cd = cdf[idx];
      float hl = hh[idx];
      float hr = hh[idx + 1];
      float alpha = (x - lc) / w;
      float out = 0.5f * (hr - hl) * w * alpha * alpha + hl * w * alpha + cd;
      out = fminf(fmaxf(out, 0.f), 1.f);
      lad += logf(alpha * (hr - hl) + hl);
      x = out;
      toff += 4 * nb + 3;
    }
    int gg = genes_oi[g];
    float region = logf(bb[gg]) + dbw[(size_t)gg * L + cl] - lse[cl] + logf((float)NT);
    contrib = lad + region;
  }
  __shared__ float red[256];
  red[threadIdx.x] = contrib;
  __syncthreads();
  for (int off = 128; off > 0; off >>= 1) {
    if (threadIdx.x < off) red[threadIdx.x] += red[threadIdx.x + off];
    __syncthreads();
  }
  if (threadIdx.x == 0) atomicAdd(acc, (double)red[0]);
}

// ---------------- KL sum-of-squares ----------------
__global__ void __launch_bounds__(256)
k_kl(const float* __restrict__ dhw, const float* __restrict__ dbw,
     const int* __restrict__ genes_oi, double* __restrict__ acc, int L, int K) {
  int g = blockIdx.x;
  int gg = genes_oi[g];
  const float* row = dhw + (size_t)gg * L * K;
  int n = L * K;
  float s1 = 0.f;
  for (int i = threadIdx.x; i < n; i += blockDim.x) { float v = row[i]; s1 += v * v; }
  float s2 = 0.f;
  const float* brow = dbw + (size_t)gg * L;
  for (int i = threadIdx.x; i < L; i += blockDim.x) { float v = brow[i]; s2 += v * v; }
  __shared__ float red[256];
  red[threadIdx.x] = s1; __syncthreads();
  for (int off = 128; off > 0; off >>= 1) {
    if (threadIdx.x < off) red[threadIdx.x] += red[threadIdx.x + off];
    __syncthreads();
  }
  if (threadIdx.x == 0) atomicAdd(acc + 1, (double)red[0]);
  __syncthreads();
  red[threadIdx.x] = s2; __syncthreads();
  for (int off = 128; off > 0; off >>= 1) {
    if (threadIdx.x < off) red[threadIdx.x] += red[threadIdx.x + off];
    __syncthreads();
  }
  if (threadIdx.x == 0) atomicAdd(acc + 2, (double)red[0]);
}

// ---------------- finalize scalar ----------------
__global__ void k_final(const double* __restrict__ acc, float* __restrict__ out,
                        long long M1, long long M2) {
  // elbo = -(sum lad + region); result = elbo - mkl.sum() - bkl.sum()
  // mkl.sum() = -0.5*S1 - M1*hl2pi ; bkl.sum() = -0.5*S2 - M2*hl2pi
  double res = -acc[0] + 0.5 * acc[1] + (double)M1 * D_HL2PI
                       + 0.5 * acc[2] + (double)M2 * D_HL2PI;
  out[0] = (float)res;
}

extern "C" void kernel_launch(void* const* d_in, const int* in_sizes, int n_in,
                              void* d_out, int out_size, void* d_ws, size_t ws_size,
                              hipStream_t stream) {
  const float* coords     = (const float*)d_in[0];
  const float* clustering = (const float*)d_in[1];
  const float* dhw        = (const float*)d_in[2];
  const float* dbw        = (const float*)d_in[3];
  const float* uh         = (const float*)d_in[4];
  const float* uw         = (const float*)d_in[5];
  const float* bb         = (const float*)d_in[6];
  const int*   genes_oi   = (const int*)d_in[7];
  const int*   lgi        = (const int*)d_in[8];
  const int*   lcg        = (const int*)d_in[9];
  // d_in[10] (localcellxgene_ix) is derivable; unused.

  int N  = in_sizes[0];
  int NT = in_sizes[6];
  int L  = in_sizes[3] / NT;   // 16
  int C  = in_sizes[1] / L;    // 1000
  int K  = in_sizes[4] / NT;   // 224
  int W  = in_sizes[5] / NT;   // 221
  int G  = in_sizes[7];        // 500
  int P  = G * L;              // 8000 pairs

  // ws layout: [acc: 4 doubles][cid: C ints][lse: L floats][tables: P*TSTRIDE floats]
  char* ws = (char*)d_ws;
  double* acc   = (double*)ws;
  int*    cid   = (int*)(ws + 256);
  size_t  lse_off = 256 + (((size_t)4 * C + 255) & ~(size_t)255);
  float*  lse   = (float*)(ws + lse_off);
  size_t  tab_off = lse_off + (((size_t)4 * L + 255) & ~(size_t)255);
  float*  tables = (float*)(ws + tab_off);
  // needed: tab_off + P*TSTRIDE*4 ~ 28.7 MB

  hipLaunchKernelGGL(k_init, dim3(1), dim3(64), 0, stream, acc);
  hipLaunchKernelGGL(k_cluster, dim3((C + 255) / 256), dim3(256), 0, stream,
                     clustering, cid, C, L);
  hipLaunchKernelGGL(k_lse, dim3(L), dim3(256), 0, stream, bb, dbw, lse, NT, L);
  hipLaunchKernelGGL(k_build, dim3(P), dim3(128), 0, stream,
                     uh, uw, dhw, genes_oi, tables, L, K, W);
  hipLaunchKernelGGL(k_main, dim3((N + 255) / 256), dim3(256), 0, stream,
                     coords, lgi, lcg, genes_oi, cid, lse, bb, dbw, tables, acc,
                     N, G, L, NT);
  hipLaunchKernelGGL(k_kl, dim3(G), dim3(256), 0, stream, dhw, dbw, genes_oi, acc, L, K);
  hipLaunchKernelGGL(k_final, dim3(1), dim3(1), 0, stream, acc, (float*)d_out,
                     (long long)G * L * K, (long long)G * L);
}